// Round 6
// baseline (244.139 us; speedup 1.0000x reference)
//
#include <hip/hip_runtime.h>

// R5: CSR machinery eliminated. The bin map is separable & input-independent:
// constexpr prefix tables XP[d][X]=#{w:ix<X}, YP[d][Y]=#{h:iy<Y} baked into
// the binary. Gather blocks own (row, <=32-bin range) segments and enumerate
// their points straight from table-driven loop bounds (no entries array);
// accumulate in an LDS [bl][c] tile; flush = coalesced 128B runs, each out
// element written exactly once (no atomics, no out zeroing).
// R4 lesson: scattered per-bin c-strided stores caused 59MB WRITE (7x ampl).

constexpr int D = 40, H = 32, W = 88, HW = H * W;       // 2816
constexpr int C = 128, NCAM = 6;
constexpr int BEV = 125, NBINS = BEV * BEV;             // 15625
constexpr int NCOLS = NCAM * HW;                        // 16896
constexpr int SEGMAX = 256;                             // target points/segment
constexpr int SLOTS  = 24;                              // max segments/row

typedef __attribute__((ext_vector_type(8))) unsigned short us8;
typedef __attribute__((ext_vector_type(4))) float f4;

__device__ __forceinline__ unsigned short f2bf(float x) {   // RNE
    unsigned u = __float_as_uint(x);
    return (unsigned short)((u + 0x7FFF + ((u >> 16) & 1)) >> 16);
}
__device__ __forceinline__ float b2f(unsigned short u) {
    return __uint_as_float(((unsigned)u) << 16);
}

// ---------------------------------------------------------------- constexpr tables
// Compile-time IEEE fp32 == device __f*_rn sequence (no contraction in
// constant evaluation). ix==125 occurs only at (d=39,w=87); iy==125 only at
// (d=39,h=31) -> excluded from prefixes (the 119 invalid points).
struct Tabs { short XP[D][126]; short YP[D][126]; };

constexpr Tabs make_tabs() {
    Tabs t{};
    for (int d = 0; d < D; ++d) {
        int dep = d + 2;
        int cntx[126] = {};
        for (int w = 0; w < W; ++w) {
            float xd = (float)(w * dep);                 // exact int
            float gx = xd / 3567.0f * 100.0f - 50.0f;
            int ix = (int)((gx + 50.0f) / 0.8f);
            if (ix < 125) cntx[ix]++;
        }
        t.XP[d][0] = 0;
        for (int X = 0; X < 125; ++X) t.XP[d][X + 1] = (short)(t.XP[d][X] + cntx[X]);
        int cnty[126] = {};
        for (int h = 0; h < H; ++h) {
            float yd = (float)(h * dep);
            float gy = yd / 1271.0f * 100.0f - 50.0f;
            int iy = (int)((gy + 50.0f) / 0.8f);
            if (iy < 125) cnty[iy]++;
        }
        t.YP[d][0] = 0;
        for (int Y = 0; Y < 125; ++Y) t.YP[d][Y + 1] = (short)(t.YP[d][Y] + cnty[Y]);
    }
    return t;
}
__device__ const Tabs g_tab = make_tabs();

// ---------------------------------------------------------------- D1: mega
// blocks [0,125)      : per-row segment scheduler (<=SLOTS segs, desc packed)
// blocks [125,1533)   : pack feat -> bf16 [hw][c][8]
// blocks [1533,1599)  : softmax -> probs_t [(d<<12)|hw][8] fp32
constexpr int SCHED_BLOCKS = BEV;                  // 125
constexpr int PACK_BLOCKS  = (C / 8) * (HW / 32);  // 1408
constexpr int SMAX_BLOCKS  = NCOLS / 256;          // 66
constexpr int MEGA_BLOCKS  = SCHED_BLOCKS + PACK_BLOCKS + SMAX_BLOCKS;

__global__ void __launch_bounds__(256) mega_kernel(
        const float* __restrict__ feat,     // [NCAM][C][HW]
        const float* __restrict__ logits,   // [NCAM][D][HW]
        float* __restrict__ probs_t,
        unsigned short* __restrict__ feat_p,
        unsigned* __restrict__ segs) {      // [BEV][SLOTS]
    __shared__ __align__(16) float tile[NCAM * 8 * 37];   // 7104 B (pack)
    __shared__ int cnt[125];
    __shared__ unsigned rowsegs[SLOTS];
    int b = blockIdx.x, t = threadIdx.x;

    if (b < SCHED_BLOCKS) {
        int iy = b;
        if (t < 125) {                                   // per-bin count, this row
            int X = t, s = 0;
#pragma unroll 8
            for (int d = 0; d < D; ++d) {
                int xc = g_tab.XP[d][X + 1] - g_tab.XP[d][X];
                int yc = g_tab.YP[d][iy + 1] - g_tab.YP[d][iy];
                s += xc * yc;
            }
            cnt[X] = s;
        }
        if (t < SLOTS) rowsegs[t] = 0xFFFFFFFFu;
        __syncthreads();
        if (t == 0) {                                    // greedy cut (125 iters)
            int ns = 0, X0 = 0, run = 0;
            for (int X = 0; X < 125; ++X) {
                int cX = cnt[X];
                if (X > X0 && ns < SLOTS - 1 &&
                    (run + cX > SEGMAX || X - X0 >= 32)) {
                    rowsegs[ns++] = ((unsigned)iy << 16) | ((unsigned)X0 << 8) | (unsigned)X;
                    X0 = X; run = 0;
                }
                run += cX;
            }
            rowsegs[ns++] = ((unsigned)iy << 16) | ((unsigned)X0 << 8) | 125u;
        }
        __syncthreads();
        if (t < SLOTS) segs[iy * SLOTS + t] = rowsegs[t];

    } else if (b < SCHED_BLOCKS + PACK_BLOCKS) {
        int b2 = b - SCHED_BLOCKS;
        int c0  = (b2 / 88) * 8;
        int hw0 = (b2 % 88) * 32;
        int cq = t >> 5, hwL = t & 31;
#pragma unroll
        for (int n = 0; n < NCAM; ++n)
            tile[(n * 8 + cq) * 37 + hwL] =
                feat[((size_t)(n * C + c0 + cq)) * HW + hw0 + hwL];
        __syncthreads();
        int hl = t >> 3, cL = t & 7;
        us8 v;
#pragma unroll
        for (int n = 0; n < NCAM; ++n)
            v[n] = f2bf(tile[(n * 8 + cL) * 37 + hl]);
        v[6] = 0; v[7] = 0;
        *(us8*)(feat_p + ((size_t)(hw0 + hl) * C + (c0 + cL)) * 8) = v;

    } else {
        int col = (b - SCHED_BLOCKS - PACK_BLOCKS) * 256 + t;   // < NCOLS exact
        int n  = col / HW;
        int hw = col - n * HW;
        const float* src = logits + ((size_t)n * D) * HW + hw;
        float v[D];
        float m = -3.402823466e+38f;
#pragma unroll
        for (int d = 0; d < D; ++d) {
            v[d] = src[(size_t)d * HW];
            m = fmaxf(m, v[d]);
        }
        float s = 0.f;
#pragma unroll
        for (int d = 0; d < D; ++d) { v[d] = expf(v[d] - m); s += v[d]; }
        float inv = 1.0f / s;
#pragma unroll
        for (int d = 0; d < D; ++d)
            probs_t[(size_t)((d << 12) | hw) * 8 + n] = v[d] * inv;
    }
}

// ---------------------------------------------------------------- D2: gather
// One block per segment slot (empty slots exit). All control flow is scalar
// (table-driven, wave-uniform). LDS tile [bl][c] pad 129: add-phase stride-1
// (2 lanes/bank, free) and flush-phase stride-129 (conflict-free).
__global__ void __launch_bounds__(128) gather_kernel(
        const unsigned short* __restrict__ feat_p,   // [hw][c][8] bf16
        const float* __restrict__ probs_t,           // [(d<<12)|hw][8] f32
        const unsigned* __restrict__ segs,
        float* __restrict__ out) {                   // [C][NBINS]
    __shared__ float T[32 * 129];
    unsigned dsc = (unsigned)__builtin_amdgcn_readfirstlane((int)segs[blockIdx.x]);
    if (dsc == 0xFFFFFFFFu) return;
    int iy = dsc >> 16, X0 = (dsc >> 8) & 0xFF, X1 = dsc & 0xFF;
    int width = X1 - X0;
    int c = threadIdx.x;

    for (int bl = 0; bl < width; ++bl) T[bl * 129 + c] = 0.f;   // own cells only

    for (int d = 0; d < D; ++d) {
        int hb = g_tab.YP[d][iy], he = g_tab.YP[d][iy + 1];
        if (hb >= he) continue;
        for (int bl = 0; bl < width; ++bl) {
            int wb = g_tab.XP[d][X0 + bl], we = g_tab.XP[d][X0 + bl + 1];
            if (wb >= we) continue;
            float acc = 0.f;
            for (int h = hb; h < he; ++h) {
                int hwb = h * W;
                for (int w = wb; w < we; ++w) {
                    int hw = hwb + w;
                    us8 fv = *(const us8*)(feat_p + ((size_t)hw * C + c) * 8);
                    const float* pp = probs_t + ((size_t)((d << 12) | hw) << 3);
                    f4 pa = *(const f4*)pp;
                    f4 pb = *(const f4*)(pp + 4);
                    acc += pa.x * b2f(fv[0]) + pa.y * b2f(fv[1])
                         + pa.z * b2f(fv[2]) + pa.w * b2f(fv[3])
                         + pb.x * b2f(fv[4]) + pb.y * b2f(fv[5]);
                }
            }
            T[bl * 129 + c] += acc;          // only thread c touches [*,c]
        }
    }
    __syncthreads();
    int binbase = iy * BEV + X0;
    for (int it = 0; it < 32; ++it) {        // coalesced: 32-lane 128B runs
        int bl = threadIdx.x & 31, cc = it * 4 + (threadIdx.x >> 5);
        if (bl < width)
            out[(size_t)cc * NBINS + binbase + bl] = T[bl * 129 + cc];
    }
}

// ---------------------------------------------------------------- launch
extern "C" void kernel_launch(void* const* d_in, const int* in_sizes, int n_in,
                              void* d_out, int out_size, void* d_ws, size_t ws_size,
                              hipStream_t stream) {
    const float* img_feat     = (const float*)d_in[0];
    const float* depth_logits = (const float*)d_in[1];
    float* out = (float*)d_out;

    char* p = (char*)d_ws;
    float*          probs_t = (float*)p;          p += (size_t)D * 4096 * 8 * 4;  // 5.24 MB
    unsigned short* feat_p  = (unsigned short*)p; p += (size_t)HW * C * 8 * 2;    // 5.77 MB
    unsigned*       segs    = (unsigned*)p;       p += (size_t)BEV * SLOTS * 4;   // 12 KB

    mega_kernel<<<MEGA_BLOCKS, 256, 0, stream>>>(
        img_feat, depth_logits, probs_t, feat_p, segs);
    gather_kernel<<<BEV * SLOTS, 128, 0, stream>>>(feat_p, probs_t, segs, out);
}

// Round 7
// 155.078 us; speedup vs baseline: 1.5743x; 1.5743x over previous
//
#include <hip/hip_runtime.h>

// R6: R5's segment ownership (atomic-free, exactly-once coalesced flush;
// WRITE_SIZE 10.5MB confirmed) + R4's throughput mechanics inside the block.
// R5 failure: 440 busy blocks x 2 waves, 1 point at a time, dependent chain
// -> latency serialization (168us, HBM 64GB/s). R6: 4 waves/block (2 c-halves
// x 2 d-groups), LDS point list enumerated by wave 0 (closed-form), batch-4
// prefetch, per-dgroup LDS tiles, register run-merge on wave-uniform bl.
// SEGMAX 128 -> ~1200 busy blocks, ~16 waves/CU.

constexpr int D = 40, H = 32, W = 88, HW = H * W;       // 2816
constexpr int C = 128, NCAM = 6;
constexpr int BEV = 125, NBINS = BEV * BEV;             // 15625
constexpr int NCOLS = NCAM * HW;                        // 16896
constexpr int SEGMAX = 128;                             // target points/segment
constexpr int SLOTS  = 56;                              // max segments/row

typedef __attribute__((ext_vector_type(8))) unsigned short us8;
typedef __attribute__((ext_vector_type(4))) float f4;

__device__ __forceinline__ unsigned short f2bf(float x) {   // RNE
    unsigned u = __float_as_uint(x);
    return (unsigned short)((u + 0x7FFF + ((u >> 16) & 1)) >> 16);
}
__device__ __forceinline__ float b2f(unsigned short u) {
    return __uint_as_float(((unsigned)u) << 16);
}

// ---------------------------------------------------------------- constexpr tables
// Compile-time IEEE fp32 == device __f*_rn sequence (verified R5: same absmax).
struct Tabs { short XP[D][126]; short YP[D][126]; };

constexpr Tabs make_tabs() {
    Tabs t{};
    for (int d = 0; d < D; ++d) {
        int dep = d + 2;
        int cntx[126] = {};
        for (int w = 0; w < W; ++w) {
            float xd = (float)(w * dep);
            float gx = xd / 3567.0f * 100.0f - 50.0f;
            int ix = (int)((gx + 50.0f) / 0.8f);
            if (ix < 125) cntx[ix]++;
        }
        t.XP[d][0] = 0;
        for (int X = 0; X < 125; ++X) t.XP[d][X + 1] = (short)(t.XP[d][X] + cntx[X]);
        int cnty[126] = {};
        for (int h = 0; h < H; ++h) {
            float yd = (float)(h * dep);
            float gy = yd / 1271.0f * 100.0f - 50.0f;
            int iy = (int)((gy + 50.0f) / 0.8f);
            if (iy < 125) cnty[iy]++;
        }
        t.YP[d][0] = 0;
        for (int Y = 0; Y < 125; ++Y) t.YP[d][Y + 1] = (short)(t.YP[d][Y] + cnty[Y]);
    }
    return t;
}
__device__ const Tabs g_tab = make_tabs();

// ---------------------------------------------------------------- D1: mega
constexpr int SCHED_BLOCKS = BEV;                  // 125
constexpr int PACK_BLOCKS  = (C / 8) * (HW / 32);  // 1408
constexpr int SMAX_BLOCKS  = NCOLS / 256;          // 66
constexpr int MEGA_BLOCKS  = SCHED_BLOCKS + PACK_BLOCKS + SMAX_BLOCKS;

__global__ void __launch_bounds__(256) mega_kernel(
        const float* __restrict__ feat,     // [NCAM][C][HW]
        const float* __restrict__ logits,   // [NCAM][D][HW]
        float* __restrict__ probs_t,
        unsigned short* __restrict__ feat_p,
        unsigned* __restrict__ segs) {      // [BEV][SLOTS]
    __shared__ __align__(16) float tile[NCAM * 8 * 37];   // pack staging
    __shared__ int cnt[125];
    __shared__ unsigned rowsegs[SLOTS];
    int b = blockIdx.x, t = threadIdx.x;

    if (b < SCHED_BLOCKS) {
        int iy = b;
        if (t < 125) {
            int X = t, s = 0;
#pragma unroll 8
            for (int d = 0; d < D; ++d) {
                int xc = g_tab.XP[d][X + 1] - g_tab.XP[d][X];
                int yc = g_tab.YP[d][iy + 1] - g_tab.YP[d][iy];
                s += xc * yc;
            }
            cnt[X] = s;
        }
        if (t < SLOTS) rowsegs[t] = 0xFFFFFFFFu;
        __syncthreads();
        if (t == 0) {                                    // greedy cut
            int ns = 0, X0 = 0, run = 0;
            for (int X = 0; X < 125; ++X) {
                int cX = cnt[X];
                if (X > X0 && ns < SLOTS - 1 &&
                    (run + cX > SEGMAX || X - X0 >= 32)) {
                    rowsegs[ns++] = ((unsigned)iy << 16) | ((unsigned)X0 << 8) | (unsigned)X;
                    X0 = X; run = 0;
                }
                run += cX;
            }
            rowsegs[ns++] = ((unsigned)iy << 16) | ((unsigned)X0 << 8) | 125u;
        }
        __syncthreads();
        if (t < SLOTS) segs[iy * SLOTS + t] = rowsegs[t];

    } else if (b < SCHED_BLOCKS + PACK_BLOCKS) {
        int b2 = b - SCHED_BLOCKS;
        int c0  = (b2 / 88) * 8;
        int hw0 = (b2 % 88) * 32;
        int cq = t >> 5, hwL = t & 31;
#pragma unroll
        for (int n = 0; n < NCAM; ++n)
            tile[(n * 8 + cq) * 37 + hwL] =
                feat[((size_t)(n * C + c0 + cq)) * HW + hw0 + hwL];
        __syncthreads();
        int hl = t >> 3, cL = t & 7;
        us8 v;
#pragma unroll
        for (int n = 0; n < NCAM; ++n)
            v[n] = f2bf(tile[(n * 8 + cL) * 37 + hl]);
        v[6] = 0; v[7] = 0;
        *(us8*)(feat_p + ((size_t)(hw0 + hl) * C + (c0 + cL)) * 8) = v;

    } else {
        int col = (b - SCHED_BLOCKS - PACK_BLOCKS) * 256 + t;   // < NCOLS exact
        int n  = col / HW;
        int hw = col - n * HW;
        const float* src = logits + ((size_t)n * D) * HW + hw;
        float v[D];
        float m = -3.402823466e+38f;
#pragma unroll
        for (int d = 0; d < D; ++d) {
            v[d] = src[(size_t)d * HW];
            m = fmaxf(m, v[d]);
        }
        float s = 0.f;
#pragma unroll
        for (int d = 0; d < D; ++d) { v[d] = expf(v[d] - m); s += v[d]; }
        float inv = 1.0f / s;
#pragma unroll
        for (int d = 0; d < D; ++d)
            probs_t[(size_t)((d << 12) | hw) * 8 + n] = v[d] * inv;
    }
}

// ---------------------------------------------------------------- D2: gather
// 256 thr = 4 waves: wave = (dgroup<<1)|chalf ; c = chalf*64+lane.
// Wave 0 enumerates point list (bl<<18|d<<12|hw) into LDS via closed-form
// per-depth offsets; waves 1-3 zero tiles. Then all waves: batch-4 prefetch,
// dgroup g consumes list positions g, g+2, ... into T[g][bl][c] with
// register run-merging on wave-uniform bl. Flush: T[0]+T[1], coalesced,
// exactly once per out element (no atomics, no out pre-zero).
constexpr int LISTCAP = 512;                        // max seg points ~284

__global__ void __launch_bounds__(256, 4) gather_kernel(
        const unsigned short* __restrict__ feat_p,   // [hw][c][8] bf16
        const float* __restrict__ probs_t,           // [(d<<12)|hw][8] f32
        const unsigned* __restrict__ segs,
        float* __restrict__ out) {                   // [C][NBINS]
    __shared__ float T[2][32][130];                  // 33.3 KB
    __shared__ unsigned list[LISTCAP];
    __shared__ int Pcnt;
    unsigned dsc = (unsigned)__builtin_amdgcn_readfirstlane((int)segs[blockIdx.x]);
    if (dsc == 0xFFFFFFFFu) return;
    int iy = dsc >> 16, X0 = (dsc >> 8) & 0xFF, X1 = dsc & 0xFF;
    int width = X1 - X0;
    int t = threadIdx.x;

    if (t < 64) {                                    // wave 0: enumerate
        int d = t;
        if (d < D) {
            int off = 0;
            for (int dd = 0; dd < d; ++dd)
                off += (g_tab.YP[dd][iy + 1] - g_tab.YP[dd][iy]) *
                       (g_tab.XP[dd][X1] - g_tab.XP[dd][X0]);
            int hb = g_tab.YP[d][iy], he = g_tab.YP[d][iy + 1];
            int p = off;
            for (int bl = 0; bl < width; ++bl) {
                int wb = g_tab.XP[d][X0 + bl], we = g_tab.XP[d][X0 + bl + 1];
                for (int h = hb; h < he; ++h)
                    for (int w = wb; w < we; ++w)
                        list[p++] = ((unsigned)bl << 18) | ((unsigned)d << 12)
                                  | (unsigned)(h * W + w);
            }
            if (d == D - 1) Pcnt = p;                // total points
        }
    } else {                                         // waves 1-3: zero tiles
        float* Tf = &T[0][0][0];
        for (int i = t - 64; i < 2 * 32 * 130; i += 192) Tf[i] = 0.f;
    }
    __syncthreads();

    int P = Pcnt;
    int lane = t & 63, wv = t >> 6;
    int dg = wv >> 1, c = (wv & 1) * 64 + lane;
    float* Tp = &T[dg][0][0];

    int npts = (P - dg + 1) >> 1;                    // this dgroup's count
    float racc = 0.f;
    int rbl = -1;                                    // current run's bl (uniform)
    for (int k0 = 0; k0 < npts; k0 += 4) {
        int kk = min(4, npts - k0);
        unsigned pk[4]; us8 fv[4]; f4 pa[4], pb[4];
#pragma unroll
        for (int j = 0; j < 4; ++j) if (j < kk) {
            pk[j] = list[dg + 2 * (k0 + j)];
            unsigned hw = pk[j] & 0xFFFu;
            fv[j] = *(const us8*)(feat_p + ((size_t)hw * C + (unsigned)c) * 8);
            const float* pp = probs_t + ((size_t)(pk[j] & 0x3FFFFu) << 3);
            pa[j] = *(const f4*)pp;
            pb[j] = *(const f4*)(pp + 4);
        }
#pragma unroll
        for (int j = 0; j < 4; ++j) if (j < kk) {
            float s = pa[j].x * b2f(fv[j][0]) + pa[j].y * b2f(fv[j][1])
                    + pa[j].z * b2f(fv[j][2]) + pa[j].w * b2f(fv[j][3])
                    + pb[j].x * b2f(fv[j][4]) + pb[j].y * b2f(fv[j][5]);
            int bl = (int)(pk[j] >> 18);             // wave-uniform
            if (bl != rbl) {                         // run-merge: fewer LDS RMWs
                if (rbl >= 0) Tp[rbl * 130 + c] += racc;
                rbl = bl; racc = s;
            } else {
                racc += s;
            }
        }
    }
    if (rbl >= 0) Tp[rbl * 130 + c] += racc;
    __syncthreads();

    int binbase = iy * BEV + X0;
    for (int it = 0; it < 16; ++it) {                // coalesced 128B runs
        int bl = t & 31, cc = it * 8 + (t >> 5);
        if (bl < width)
            out[(size_t)cc * NBINS + binbase + bl] = T[0][bl][cc] + T[1][bl][cc];
    }
}

// ---------------------------------------------------------------- launch
extern "C" void kernel_launch(void* const* d_in, const int* in_sizes, int n_in,
                              void* d_out, int out_size, void* d_ws, size_t ws_size,
                              hipStream_t stream) {
    const float* img_feat     = (const float*)d_in[0];
    const float* depth_logits = (const float*)d_in[1];
    float* out = (float*)d_out;

    char* p = (char*)d_ws;
    float*          probs_t = (float*)p;          p += (size_t)D * 4096 * 8 * 4;  // 5.24 MB
    unsigned short* feat_p  = (unsigned short*)p; p += (size_t)HW * C * 8 * 2;    // 5.77 MB
    unsigned*       segs    = (unsigned*)p;       p += (size_t)BEV * SLOTS * 4;   // 28 KB

    mega_kernel<<<MEGA_BLOCKS, 256, 0, stream>>>(
        img_feat, depth_logits, probs_t, feat_p, segs);
    gather_kernel<<<BEV * SLOTS, 256, 0, stream>>>(feat_p, probs_t, segs, out);
}